// Round 9
// baseline (7722.530 us; speedup 1.0000x reference)
//
#include <hip/hip_runtime.h>
#include <math.h>

typedef unsigned short u16;
typedef unsigned int   u32;
typedef unsigned long long u64;
typedef __attribute__((ext_vector_type(8))) short short8;
typedef __attribute__((ext_vector_type(4))) float f32x4;

__device__ __forceinline__ float bf2f(u16 v) { return __uint_as_float(((u32)v) << 16); }
__device__ __forceinline__ u16 f2bf(float f) {
    u32 u = __float_as_uint(f);
    u32 r = (u + 0x7fffu + ((u >> 16) & 1u)) >> 16;
    return (u16)r;
}
__device__ __forceinline__ u32 pk2(float a, float b) {
    return ((u32)f2bf(a)) | (((u32)f2bf(b)) << 16);
}
__device__ __forceinline__ float sigm(float x) { return 1.f / (1.f + __expf(-x)); }
__device__ __forceinline__ f32x4 mfma16(short8 a, short8 b, f32x4 c) {
    return __builtin_amdgcn_mfma_f32_16x16x32_bf16(a, b, c, 0, 0, 0);
}
__device__ __forceinline__ short8 ld8bf(const float* p) {
    short8 r;
#pragma unroll
    for (int j = 0; j < 8; ++j) r[j] = (short)f2bf(p[j]);
    return r;
}
// 16B cache-bypassing load straight to/from the coherence point.
__device__ __forceinline__ short8 ldg16cv(const u16* p) {
    short8 r;
    asm volatile("global_load_dwordx4 %0, %1, off sc0 sc1" : "=v"(r) : "v"(p));
    return r;
}
__device__ __forceinline__ void waitvm() {
    asm volatile("s_waitcnt vmcnt(0)" ::: "memory");
}

#define FLAG_STRIDE 16   /* ints -> 64B per flag slot (store isolation!) */
#define NPAR 8           /* h ring depth */
#define BIGF (1 << 26)
#define XL_OFF 16384000
#define PS_OFF 16384016

// ws layout (bytes)
#define WS_FLAGS   0        /* 352 slots x 64B, padded to 32768 */
#define WS_HBUF_F  32768    /* 3 layers x 8 par x 16x512 bf16 = 393216 */
#define WS_HBUF_W  425984   /* 8 par x 16x256 bf16 = 65536 */
#define WS_REPS    491520   /* 1600x512 fp32 = 3276800 -> 3768320 */
#define WS_RW      3768320  /* 1600x256 bf16 = 819200 */
#define WS_HSEQ    4587520  /* 1600x256 fp32 = 1638400 */
#define WS_FPWB    6225920  /* 512x512 bf16 = 524288 -> 6750208 */
#define WS_WMAP    6750208  /* 16x2000 int = 128000 -> 6878208 */
#define WS_INV     6878208  /* 1600 fp32 = 6400 -> 6884608 */

// ---------------------------------------------------------------------------
// Persistent 3-layer frame LSTM. 192 WGs (64 per layer), 128 threads each.
// ROUND-0 CHAMPION SYNC PROTOCOL VERBATIM (8/8 deviations regressed).
// NEW (this round): the L2 WGs' idle wave1 does, in the shadow of wave0's
// gate-math/publish/ack phase (~1000 cy):
//  * frame projection of y[:, t-1, own 8 cols] from AsOwn (= h_{t-1}, full
//    512 K) via 16 MFMAs + fpWb weights in regs; t<xl mask per A-row;
//    y = fpb for masked rows (matches reference h*tmask @ W + b).
//  * tail-mean pooling: wmap[b][t] (precomputed; windows are disjoint since
//    word spans partition [0,T)) selects the open window; fp32 running
//    accumulators fed from sH (wave0's fp32 h, double-buffered 1KB LDS --
//    identical precision to the old k_pool reading fp32 h3) flush on close.
// Deletes k_pool / k_frame_proj / k_xlens and the 65MB h3 store+re-read.
// ---------------------------------------------------------------------------
template<int KTIN, bool L0, bool PROJ>
__device__ __forceinline__ void frame_body(
    const int layer, const int kwg,
    const float* __restrict__ Wih, const float* __restrict__ Whh, const float* __restrict__ bias,
    const float* __restrict__ x, u16* __restrict__ hbuf, int* __restrict__ flags,
    float* __restrict__ yout, const u16* __restrict__ fpWb, const float* __restrict__ fpb,
    const int* __restrict__ xlens, const int* __restrict__ wmapp,
    const float* __restrict__ invc, float* __restrict__ reps,
    float* sC, float* sH, u16* sxpad, u16* AsIn, u16* AsOwn)
{
    const int tid  = threadIdx.x;
    const int lane = tid & 63;
    const int wave = tid >> 6;
    const int n16  = lane & 15;
    const int quad = lane >> 4;
    const int koff = quad * 8;

    if (L0) {                                            // zero the x pad cols [80,96)
        for (int e = tid; e < 256; e += 128) sxpad[(e >> 4) * 96 + 80 + (e & 15)] = 0;
    }

    // B fragments in registers. wave0 -> tile (i|f), wave1 -> tile (g|o).
    const int grow = wave * 1024 + ((n16 >> 3) * 512) + kwg * 8 + (n16 & 7);
    short8 bfr[KTIN + 16];
#pragma unroll
    for (int kt = 0; kt < KTIN; ++kt) {
        short8 v = {0,0,0,0,0,0,0,0};
        const int k = kt * 32 + koff;
        if (L0) { if (k + 8 <= 80) v = ld8bf(Wih + grow * 80 + k); }
        else    { v = ld8bf(Wih + (size_t)grow * 512 + k); }
        bfr[kt] = v;
    }
#pragma unroll
    for (int kt = 0; kt < 16; ++kt)
        bfr[KTIN + kt] = ld8bf(Whh + (size_t)grow * 512 + kt * 32 + koff);

    // gate phase (tid<64): lane handles batch gb, cols c0,c0+1; c-state in regs
    const int gb = tid & 15;
    const int gp4 = (tid >> 4) & 3;
    const int c0 = kwg * 8 + gp4 * 2;
    const float bI0 = bias[c0],        bI1 = bias[c0 + 1];
    const float bF0 = bias[512 + c0],  bF1 = bias[512 + c0 + 1];
    const float bG0 = bias[1024 + c0], bG1 = bias[1024 + c0 + 1];
    const float bO0 = bias[1536 + c0], bO1 = bias[1536 + c0 + 1];
    float cp0 = 0.f, cp1 = 0.f;

    // PROJ-only state (wave1 shadow work)
    short8 wpr[PROJ ? 16 : 1];
    int xlr = 0; float fpbr = 0.f;
    float pa0 = 0.f, pa1 = 0.f; int pw = -1;
    const int pb = lane >> 2;            // pool batch 0..15
    const int plc = (lane & 3) * 2;      // pool local col 0,2,4,6
    if (PROJ) {
        const int prow = kwg * 8 + (n16 & 7);
#pragma unroll
        for (int kt = 0; kt < 16; ++kt)
            wpr[kt] = *(const short8*)(fpWb + (size_t)prow * 512 + kt * 32 + koff);
        xlr = xlens[n16];
        if (n16 < 8) fpbr = fpb[kwg * 8 + n16];
    }

    // flag slot bases: prev layer = slot(layer), own = slot(layer+1), next = slot(layer+2)
    const int* fP = flags + (layer * 64) * FLAG_STRIDE;
    const int* fO = flags + ((layer + 1) * 64) * FLAG_STRIDE;
    const int* fN = flags + ((layer + 2) * 64) * FLAG_STRIDE;
    int* myflag   = flags + ((layer + 1) * 64 + kwg) * FLAG_STRIDE;
    __syncthreads();

    for (int t = 0; t < 2000; ++t) {
        // ---- wait for producers / ring anti-dependency ----
        if (wave == 0) {
            int guard = 0;
            for (;;) {
                const int fp = __hip_atomic_load(fP + lane * FLAG_STRIDE, __ATOMIC_RELAXED, __HIP_MEMORY_SCOPE_AGENT);
                const int fo = __hip_atomic_load(fO + lane * FLAG_STRIDE, __ATOMIC_RELAXED, __HIP_MEMORY_SCOPE_AGENT);
                const int fn = __hip_atomic_load(fN + lane * FLAG_STRIDE, __ATOMIC_RELAXED, __HIP_MEMORY_SCOPE_AGENT);
                if (__all((fp >= t + 1) && (fo >= t) && (fn >= t - 7))) break;
                if (++guard > (1 << 22)) break;   // anti-hang escape
                __builtin_amdgcn_s_sleep(1);
            }
        }
        __syncthreads();

        // ---- stage h (and x) into LDS: one 16B bypass load per chunk ----
        const u16* hown = hbuf + ((size_t)(layer * NPAR + ((t + 7) & 7))) * 8192;
        short8 rin[8], rown[8];
        float4 xv0, xv1, xv2;
        if (L0) {
            const int e0 = tid, e1 = tid + 128, e2 = tid + 256;
            xv0 = *(const float4*)(x + ((size_t)(e0 / 20) * 2000 + t) * 80 + (e0 % 20) * 4);
            xv1 = *(const float4*)(x + ((size_t)(e1 / 20) * 2000 + t) * 80 + (e1 % 20) * 4);
            if (e2 < 320)
                xv2 = *(const float4*)(x + ((size_t)(e2 / 20) * 2000 + t) * 80 + (e2 % 20) * 4);
        } else {
            const u16* hin = hbuf + ((size_t)((layer - 1) * NPAR + (t & 7))) * 8192;
#pragma unroll
            for (int i = 0; i < 8; ++i) rin[i] = ldg16cv(hin + (tid + 128 * i) * 8);
        }
#pragma unroll
        for (int i = 0; i < 8; ++i) rown[i] = ldg16cv(hown + (tid + 128 * i) * 8);
        waitvm();
        if (L0) {
            const int e0 = tid, e1 = tid + 128, e2 = tid + 256;
            u32* d0 = (u32*)(sxpad + (e0 / 20) * 96 + (e0 % 20) * 4);
            d0[0] = pk2(xv0.x, xv0.y); d0[1] = pk2(xv0.z, xv0.w);
            u32* d1 = (u32*)(sxpad + (e1 / 20) * 96 + (e1 % 20) * 4);
            d1[0] = pk2(xv1.x, xv1.y); d1[1] = pk2(xv1.z, xv1.w);
            if (e2 < 320) {
                u32* d2 = (u32*)(sxpad + (e2 / 20) * 96 + (e2 % 20) * 4);
                d2[0] = pk2(xv2.x, xv2.y); d2[1] = pk2(xv2.z, xv2.w);
            }
        }
#pragma unroll
        for (int i = 0; i < 8; ++i) {
            const int c = tid + 128 * i;
            const int row = c >> 6, col8 = (c & 63) << 3;
            if (!L0) *(short8*)(AsIn + row * 520 + col8) = rin[i];
            *(short8*)(AsOwn + row * 520 + col8) = rown[i];
        }
        __syncthreads();

        // ---- gate GEMM ----
        f32x4 acc[4] = {{0,0,0,0},{0,0,0,0},{0,0,0,0},{0,0,0,0}};
#pragma unroll
        for (int kt = 0; kt < KTIN; ++kt) {
            short8 a;
            if (L0) a = *(const short8*)(sxpad + n16 * 96 + kt * 32 + koff);
            else    a = *(const short8*)(AsIn + n16 * 520 + kt * 32 + koff);
            acc[kt & 3] = mfma16(a, bfr[kt], acc[kt & 3]);
        }
#pragma unroll
        for (int kt = 0; kt < 16; ++kt) {
            short8 a = *(const short8*)(AsOwn + n16 * 520 + kt * 32 + koff);
            acc[(KTIN + kt) & 3] = mfma16(a, bfr[KTIN + kt], acc[(KTIN + kt) & 3]);
        }
        const f32x4 C = acc[0] + acc[1] + acc[2] + acc[3];
#pragma unroll
        for (int r = 0; r < 4; ++r)
            sC[(wave * 16 + quad * 4 + r) * 17 + n16] = C[r];   // [wave*16+batch][gate], padded
        __syncthreads();

        // ---- gate math + publish (wave0) | proj+pool shadow (wave1, PROJ) ----
        if (tid < 64) {
            const int b = gb, p = gp4;
            float hn0, hn1;
            {
                const float gi = sC[b * 17 + p * 2]            + bI0;
                const float gf = sC[b * 17 + 8 + p * 2]        + bF0;
                const float gg = sC[(16 + b) * 17 + p * 2]     + bG0;
                const float go = sC[(16 + b) * 17 + 8 + p * 2] + bO0;
                const float cn = sigm(gf) * cp0 + sigm(gi) * tanhf(gg);
                hn0 = sigm(go) * tanhf(cn);
                cp0 = cn;
            }
            {
                const float gi = sC[b * 17 + p * 2 + 1]            + bI1;
                const float gf = sC[b * 17 + 8 + p * 2 + 1]        + bF1;
                const float gg = sC[(16 + b) * 17 + p * 2 + 1]     + bG1;
                const float go = sC[(16 + b) * 17 + 8 + p * 2 + 1] + bO1;
                const float cn = sigm(gf) * cp1 + sigm(gi) * tanhf(gg);
                hn1 = sigm(go) * tanhf(cn);
                cp1 = cn;
            }
            if (PROJ) {                                  // fp32 h for the pool shadow
                sH[(t & 1) * 128 + b * 8 + p * 2] = hn0;
                sH[(t & 1) * 128 + b * 8 + p * 2 + 1] = hn1;
            }
            const u32 pk = ((u32)f2bf(hn0)) | (((u32)f2bf(hn1)) << 16);
            u32* hdst = (u32*)(hbuf + ((size_t)(layer * NPAR + (t & 7))) * 8192 + b * 512 + kwg * 8 + p * 2);
            __hip_atomic_store(hdst, pk, __ATOMIC_RELAXED, __HIP_MEMORY_SCOPE_AGENT);
            waitvm();  // ack at coherence point before flag
            if (tid == 0)
                __hip_atomic_store(myflag, t + 1, __ATOMIC_RELAXED, __HIP_MEMORY_SCOPE_AGENT);
        } else if (PROJ) {
            if (t > 0) {
                // proj y[:, t-1, own cols] from AsOwn (bf16, == old k_frame_proj)
                const bool rowok = (t - 1) < xlr;
                const short8 z8 = {0,0,0,0,0,0,0,0};
                f32x4 pc = {0, 0, 0, 0};
#pragma unroll
                for (int kt = 0; kt < 16; ++kt) {
                    short8 a = rowok ? *(const short8*)(AsOwn + n16 * 520 + kt * 32 + koff) : z8;
                    pc = mfma16(a, wpr[kt], pc);
                }
                if (n16 < 8) {
#pragma unroll
                    for (int r = 0; r < 4; ++r)
                        yout[((size_t)((quad * 4 + r) * 2000 + (t - 1))) * 512 + kwg * 8 + n16] = pc[r] + fpbr;
                }
                // pool h_{t-1} (fp32 from sH) into running window accumulators
                const int w = wmapp[pb * 2000 + (t - 1)];
                if (w != pw) {
                    if (pw >= 0) {
                        const float iv = invc[pb * 100 + pw];
                        reps[((size_t)(pb * 100 + pw)) * 512 + kwg * 8 + plc]     = pa0 * iv;
                        reps[((size_t)(pb * 100 + pw)) * 512 + kwg * 8 + plc + 1] = pa1 * iv;
                    }
                    pa0 = pa1 = 0.f; pw = w;
                }
                if (w >= 0) {
                    pa0 += sH[((t - 1) & 1) * 128 + pb * 8 + plc];
                    pa1 += sH[((t - 1) & 1) * 128 + pb * 8 + plc + 1];
                }
            }
        }
    }

    // ---- PROJ epilogue: project + pool h_1999, flush open windows ----
    if (PROJ) {
        if (wave == 0) {
            int guard = 0;
            for (;;) {
                const int fo = __hip_atomic_load(fO + lane * FLAG_STRIDE, __ATOMIC_RELAXED, __HIP_MEMORY_SCOPE_AGENT);
                if (__all(fo >= 2000)) break;
                if (++guard > (1 << 22)) break;
                __builtin_amdgcn_s_sleep(1);
            }
        }
        __syncthreads();
        const u16* hown = hbuf + ((size_t)(layer * NPAR + 7)) * 8192;   // slot 7 = h_1999
        short8 rown[8];
#pragma unroll
        for (int i = 0; i < 8; ++i) rown[i] = ldg16cv(hown + (tid + 128 * i) * 8);
        waitvm();
#pragma unroll
        for (int i = 0; i < 8; ++i) {
            const int c = tid + 128 * i;
            *(short8*)(AsOwn + (c >> 6) * 520 + ((c & 63) << 3)) = rown[i];
        }
        __syncthreads();
        if (wave == 1) {
            const bool rowok = 1999 < xlr;
            const short8 z8 = {0,0,0,0,0,0,0,0};
            f32x4 pc = {0, 0, 0, 0};
#pragma unroll
            for (int kt = 0; kt < 16; ++kt) {
                short8 a = rowok ? *(const short8*)(AsOwn + n16 * 520 + kt * 32 + koff) : z8;
                pc = mfma16(a, wpr[kt], pc);
            }
            if (n16 < 8) {
#pragma unroll
                for (int r = 0; r < 4; ++r)
                    yout[((size_t)((quad * 4 + r) * 2000 + 1999)) * 512 + kwg * 8 + n16] = pc[r] + fpbr;
            }
            const int w = wmapp[pb * 2000 + 1999];
            if (w != pw) {
                if (pw >= 0) {
                    const float iv = invc[pb * 100 + pw];
                    reps[((size_t)(pb * 100 + pw)) * 512 + kwg * 8 + plc]     = pa0 * iv;
                    reps[((size_t)(pb * 100 + pw)) * 512 + kwg * 8 + plc + 1] = pa1 * iv;
                }
                pa0 = pa1 = 0.f; pw = w;
            }
            if (w >= 0) {
                pa0 += sH[128 + pb * 8 + plc];      // (1999 & 1) == 1
                pa1 += sH[128 + pb * 8 + plc + 1];
            }
            if (pw >= 0) {
                const float iv = invc[pb * 100 + pw];
                reps[((size_t)(pb * 100 + pw)) * 512 + kwg * 8 + plc]     = pa0 * iv;
                reps[((size_t)(pb * 100 + pw)) * 512 + kwg * 8 + plc + 1] = pa1 * iv;
            }
        }
    }
}

__global__ __launch_bounds__(128, 1) void k_frame_lstm(
    const float* __restrict__ x,
    const float* __restrict__ Wih0, const float* __restrict__ Whh0, const float* __restrict__ b0,
    const float* __restrict__ Wih1, const float* __restrict__ Whh1, const float* __restrict__ b1,
    const float* __restrict__ Wih2, const float* __restrict__ Whh2, const float* __restrict__ b2,
    u16* hbuf, int* flags, float* yout,
    const u16* __restrict__ fpWb, const float* __restrict__ fpb,
    const int* __restrict__ xlens, const int* __restrict__ wmapp,
    const float* __restrict__ invc, float* __restrict__ reps)
{
    __shared__ __align__(16) u16 sxpad[16 * 96];
    __shared__ __align__(16) u16 AsIn[16 * 520];
    __shared__ __align__(16) u16 AsOwn[16 * 520];
    __shared__ float sC[32 * 17];
    __shared__ float sH[256];
    const int wgid = blockIdx.x;
    const int layer = wgid >> 6;
    const int kwg = wgid & 63;
    if (layer == 0)      frame_body<3,  true,  false>(0, kwg, Wih0, Whh0, b0, x, hbuf, flags, yout, fpWb, fpb, xlens, wmapp, invc, reps, sC, sH, sxpad, AsIn, AsOwn);
    else if (layer == 1) frame_body<16, false, false>(1, kwg, Wih1, Whh1, b1, x, hbuf, flags, yout, fpWb, fpb, xlens, wmapp, invc, reps, sC, sH, sxpad, AsIn, AsOwn);
    else                 frame_body<16, false, true >(2, kwg, Wih2, Whh2, b2, x, hbuf, flags, yout, fpWb, fpb, xlens, wmapp, invc, reps, sC, sH, sxpad, AsIn, AsOwn);
}

// ---------------------------------------------------------------------------
// wmap precompute: wmap[b][t] = word index whose tail window contains t
// (windows are disjoint: word spans partition [0,T)), invc[b][w] = 1/cnt.
// Also writes the x_lens output floats (folds old k_xlens).
// ---------------------------------------------------------------------------
__global__ void k_wmap(const int* __restrict__ x_lens, const int* __restrict__ wstarts,
                       const int* __restrict__ wends, const int* __restrict__ wlens,
                       const int* __restrict__ tailp, int* __restrict__ wmap,
                       float* __restrict__ invc, float* __restrict__ out)
{
    const int b = blockIdx.x;        // 16
    const int tid = threadIdx.x;     // 256
    for (int t = tid; t < 2000; t += 256) wmap[b * 2000 + t] = -1;
    if (tid == 0) out[XL_OFF + b] = (float)x_lens[b];
    __syncthreads();
    if (tid < 100) {
        const int w = tid;
        const int xl = x_lens[b];
        const int we = wends[b * 100 + w];
        const int s0 = wstarts[b * 100 + w];
        const int wl = wlens[b];
        const int tail = tailp[0];
        int ef = we < xl ? we : xl;
        int sf = s0 > 0 ? s0 : 0;
        int i0 = ef - tail; if (i0 < sf) i0 = sf;
        const bool valid = (w < wl) && (we > 0) && (ef > sf) && (ef > i0);
        invc[b * 100 + w] = valid ? 1.f / (float)(ef - i0) : 0.f;
        if (valid) {
            for (int t = i0; t < ef; ++t) wmap[b * 2000 + t] = w;
        }
    }
}

// ---------------------------------------------------------------------------
// Persistent word LSTM: 32 WGs x 128 threads, 100 steps, H=256, K=256+256.
// Round-0 protocol; register c-state; hseq stores after the flag. (R8 verbatim)
// ---------------------------------------------------------------------------
__global__ __launch_bounds__(128, 1) void k_word_lstm(
    const u16* __restrict__ rW, const float* __restrict__ Wih,
    const float* __restrict__ Whh, const float* __restrict__ bias,
    u16* __restrict__ hbufw, int* __restrict__ flags, float* __restrict__ hseq)
{
    __shared__ float sC[32 * 17];
    const int tid = threadIdx.x;
    const int lane = tid & 63;
    const int wave = tid >> 6;
    const int n16 = lane & 15;
    const int quad = lane >> 4;
    const int koff = quad * 8;
    const int kwg = blockIdx.x;  // 0..31

    const int grow = wave * 512 + ((n16 >> 3) * 256) + kwg * 8 + (n16 & 7);
    short8 bfr[16];
#pragma unroll
    for (int kt = 0; kt < 8; ++kt) bfr[kt]     = ld8bf(Wih + (size_t)grow * 256 + kt * 32 + koff);
#pragma unroll
    for (int kt = 0; kt < 8; ++kt) bfr[8 + kt] = ld8bf(Whh + (size_t)grow * 256 + kt * 32 + koff);
    const int gb = tid & 15;
    const int gp4 = (tid >> 4) & 3;
    const int c0 = kwg * 8 + gp4 * 2;
    const float bI0 = bias[c0],       bI1 = bias[c0 + 1];
    const float bF0 = bias[256 + c0], bF1 = bias[256 + c0 + 1];
    const float bG0 = bias[512 + c0], bG1 = bias[512 + c0 + 1];
    const float bO0 = bias[768 + c0], bO1 = bias[768 + c0 + 1];
    float cp0 = 0.f, cp1 = 0.f;
    const int* fO = flags + 320 * FLAG_STRIDE;
    int* myflag   = flags + (320 + kwg) * FLAG_STRIDE;
    __syncthreads();
    const int aoff = n16 * 256 + koff;

    for (int t = 0; t < 100; ++t) {
        if (wave == 0) {
            int guard = 0;
            for (;;) {
                const int fo = (lane < 32)
                    ? __hip_atomic_load(fO + lane * FLAG_STRIDE, __ATOMIC_RELAXED, __HIP_MEMORY_SCOPE_AGENT)
                    : BIGF;
                if (__all(fo >= t)) break;
                if (++guard > (1 << 22)) break;
                __builtin_amdgcn_s_sleep(1);
            }
        }
        __syncthreads();
        const u16* hown = hbufw + ((size_t)((t + 7) & 7)) * 4096;
        short8 ha[8];
#pragma unroll
        for (int kt = 0; kt < 8; ++kt) ha[kt] = ldg16cv(hown + aoff + kt * 32);
        f32x4 acc[4] = {{0,0,0,0},{0,0,0,0},{0,0,0,0},{0,0,0,0}};
#pragma unroll
        for (int kt = 0; kt < 8; ++kt) {
            short8 a = *(const short8*)(rW + ((size_t)(n16 * 100 + t)) * 256 + koff + kt * 32);
            acc[kt & 3] = mfma16(a, bfr[kt], acc[kt & 3]);
        }
        waitvm();
#pragma unroll
        for (int kt = 0; kt < 8; ++kt)
            acc[kt & 3] = mfma16(ha[kt], bfr[8 + kt], acc[kt & 3]);
        const f32x4 C = acc[0] + acc[1] + acc[2] + acc[3];
#pragma unroll
        for (int r = 0; r < 4; ++r) sC[(wave * 16 + quad * 4 + r) * 17 + n16] = C[r];
        __syncthreads();
        if (tid < 64) {
            const int b = gb, p = gp4;
            float hn0, hn1;
            {
                const float gi = sC[b * 17 + p * 2]            + bI0;
                const float gf = sC[b * 17 + 8 + p * 2]        + bF0;
                const float gg = sC[(16 + b) * 17 + p * 2]     + bG0;
                const float go = sC[(16 + b) * 17 + 8 + p * 2] + bO0;
                const float cn = sigm(gf) * cp0 + sigm(gi) * tanhf(gg);
                hn0 = sigm(go) * tanhf(cn);
                cp0 = cn;
            }
            {
                const float gi = sC[b * 17 + p * 2 + 1]            + bI1;
                const float gf = sC[b * 17 + 8 + p * 2 + 1]        + bF1;
                const float gg = sC[(16 + b) * 17 + p * 2 + 1]     + bG1;
                const float go = sC[(16 + b) * 17 + 8 + p * 2 + 1] + bO1;
                const float cn = sigm(gf) * cp1 + sigm(gi) * tanhf(gg);
                hn1 = sigm(go) * tanhf(cn);
                cp1 = cn;
            }
            const u32 pk = ((u32)f2bf(hn0)) | (((u32)f2bf(hn1)) << 16);
            u32* hdst = (u32*)(hbufw + ((size_t)(t & 7)) * 4096 + b * 256 + kwg * 8 + p * 2);
            __hip_atomic_store(hdst, pk, __ATOMIC_RELAXED, __HIP_MEMORY_SCOPE_AGENT);
            waitvm();  // ack before flag
            if (tid == 0)
                __hip_atomic_store(myflag, t + 1, __ATOMIC_RELAXED, __HIP_MEMORY_SCOPE_AGENT);
            float* hp = hseq + ((size_t)(b * 100 + t)) * 256 + kwg * 8 + p * 2;   // after flag
            hp[0] = hn0; hp[1] = hn1;
        }
    }
}

// ---------------------------------------------------------------------------
// word_proj: Linear(512->256) + LayerNorm + exact GELU per (b,w) row.
// ---------------------------------------------------------------------------
__global__ void k_word_proj(const float* __restrict__ reps, const float* __restrict__ wpW,
                            const float* __restrict__ wpb, const float* __restrict__ lnW,
                            const float* __restrict__ lnB, u16* __restrict__ rW)
{
    __shared__ float sx[512];
    __shared__ float red[512];
    const int tid = threadIdx.x;
    const int row = blockIdx.x;
    for (int k = tid; k < 512; k += 256) sx[k] = reps[(size_t)row * 512 + k];
    __syncthreads();
    float acc = wpb[tid];
    const float4* wr = (const float4*)(wpW + (size_t)tid * 512);
    for (int k4 = 0; k4 < 128; ++k4) {
        const float4 w = wr[k4];
        acc += sx[k4 * 4] * w.x + sx[k4 * 4 + 1] * w.y + sx[k4 * 4 + 2] * w.z + sx[k4 * 4 + 3] * w.w;
    }
    red[tid] = acc; red[256 + tid] = acc * acc;
    __syncthreads();
    for (int s = 128; s > 0; s >>= 1) {
        if (tid < s) { red[tid] += red[tid + s]; red[256 + tid] += red[256 + tid + s]; }
        __syncthreads();
    }
    const float mu = red[0] * (1.f / 256.f);
    float var = red[256] * (1.f / 256.f) - mu * mu;
    if (var < 0.f) var = 0.f;
    const float xn = (acc - mu) * rsqrtf(var + 1e-5f);
    const float yv = xn * lnW[tid] + lnB[tid];
    const float g = 0.5f * yv * (1.0f + erff(yv * 0.70710678118654752f));
    rW[(size_t)row * 256 + tid] = f2bf(g);
}

// ---------------------------------------------------------------------------
// pred_sem = mask(hseq) @ spW^T + spb  (fp32 vector math)
// ---------------------------------------------------------------------------
__global__ void k_pred(const float* __restrict__ hseq, const int* __restrict__ wlens,
                       const float* __restrict__ spW, const float* __restrict__ spb,
                       float* __restrict__ out)
{
    __shared__ float sh[256];
    const int tid = threadIdx.x;
    const int rw = blockIdx.x;
    const int b = rw / 100, w = rw - b * 100;
    int wl = wlens[b]; if (wl < 1) wl = 1;
    const bool valid = (w < wl);
    sh[tid] = valid ? hseq[(size_t)rw * 256 + tid] : 0.f;
    __syncthreads();
    for (int o = tid; o < 512; o += 256) {
        float acc = spb[o];
        const float4* wr = (const float4*)(spW + (size_t)o * 256);
        for (int k4 = 0; k4 < 64; ++k4) {
            const float4 wv = wr[k4];
            acc += sh[k4 * 4] * wv.x + sh[k4 * 4 + 1] * wv.y + sh[k4 * 4 + 2] * wv.z + sh[k4 * 4 + 3] * wv.w;
        }
        out[PS_OFF + (size_t)rw * 512 + o] = acc;
    }
}

// Pre-cast fpW (512x512 fp32) -> bf16
__global__ void k_cvt(const float* __restrict__ src, u16* __restrict__ dst)
{
    const int e = blockIdx.x * 256 + threadIdx.x;   // 65536 float4s
    const float4 v = *(const float4*)(src + (size_t)e * 4);
    u32* d = (u32*)(dst + (size_t)e * 4);
    d[0] = pk2(v.x, v.y);
    d[1] = pk2(v.z, v.w);
}

// Init flags (with BIG sentinels for dummy layers) + zero h rings + zero reps.
// Covers bytes [0, 3768320): 3680 blocks x 256 threads x 1 u32.
__global__ void k_init(u32* __restrict__ p)
{
    const int idx = blockIdx.x * 256 + threadIdx.x;
    u32 v = 0u;
    if (idx < 8192) {                      // flag area (32 KB)
        const int slot = idx >> 4;
        if (slot < 64 || (slot >= 256 && slot < 320)) v = (u32)BIGF;
    }
    p[idx] = v;
}

// ---------------------------------------------------------------------------
extern "C" void kernel_launch(void* const* d_in, const int* in_sizes, int n_in,
                              void* d_out, int out_size, void* d_ws, size_t ws_size,
                              hipStream_t stream)
{
    (void)in_sizes; (void)n_in; (void)out_size; (void)ws_size;
    const float* x    = (const float*)d_in[0];
    const int* x_lens = (const int*)d_in[1];
    const int* wstart = (const int*)d_in[2];
    const int* wend   = (const int*)d_in[3];
    const int* wlen   = (const int*)d_in[4];
    const int* tailp  = (const int*)d_in[5];
    const float* Wih0 = (const float*)d_in[6];
    const float* Whh0 = (const float*)d_in[7];
    const float* b0   = (const float*)d_in[8];
    const float* Wih1 = (const float*)d_in[9];
    const float* Whh1 = (const float*)d_in[10];
    const float* b1   = (const float*)d_in[11];
    const float* Wih2 = (const float*)d_in[12];
    const float* Whh2 = (const float*)d_in[13];
    const float* b2   = (const float*)d_in[14];
    const float* fpW  = (const float*)d_in[15];
    const float* fpb  = (const float*)d_in[16];
    const float* wpW  = (const float*)d_in[17];
    const float* wpb  = (const float*)d_in[18];
    const float* lnW  = (const float*)d_in[19];
    const float* lnB  = (const float*)d_in[20];
    const float* wWih = (const float*)d_in[21];
    const float* wWhh = (const float*)d_in[22];
    const float* wb   = (const float*)d_in[23];
    const float* spW  = (const float*)d_in[24];
    const float* spb  = (const float*)d_in[25];

    float* out = (float*)d_out;
    char* ws = (char*)d_ws;
    int* flags  = (int*)(ws + WS_FLAGS);
    u16* hbufF  = (u16*)(ws + WS_HBUF_F);
    u16* hbufW  = (u16*)(ws + WS_HBUF_W);
    float* reps = (float*)(ws + WS_REPS);
    u16* rW     = (u16*)(ws + WS_RW);
    float* hseq = (float*)(ws + WS_HSEQ);
    u16* fpWb   = (u16*)(ws + WS_FPWB);
    int* wmap   = (int*)(ws + WS_WMAP);
    float* invc = (float*)(ws + WS_INV);

    k_init<<<3680, 256, 0, stream>>>((u32*)d_ws);
    k_cvt<<<256, 256, 0, stream>>>(fpW, fpWb);
    k_wmap<<<16, 256, 0, stream>>>(x_lens, wstart, wend, wlen, tailp, wmap, invc, out);
    k_frame_lstm<<<192, 128, 0, stream>>>(x, Wih0, Whh0, b0, Wih1, Whh1, b1,
                                          Wih2, Whh2, b2, hbufF, flags, out,
                                          fpWb, fpb, x_lens, wmap, invc, reps);
    k_word_proj<<<1600, 256, 0, stream>>>(reps, wpW, wpb, lnW, lnB, rW);
    k_word_lstm<<<32, 128, 0, stream>>>(rW, wWih, wWhh, wb, hbufW, flags, hseq);
    k_pred<<<1600, 256, 0, stream>>>(hseq, wlen, spW, spb, out);
}